// Round 1
// baseline (685.830 us; speedup 1.0000x reference)
//
#include <hip/hip_runtime.h>
#include <stdint.h>

#define T_LEN 2048
#define KAUG  1056
#define M_TOT 65536

typedef __attribute__((ext_vector_type(8))) short short8;
typedef __attribute__((ext_vector_type(4))) float f32x4;
typedef unsigned int u32;
typedef unsigned short u16;

__device__ __forceinline__ u16 bf16_rn(float f){
  u32 u = __builtin_bit_cast(u32, f);
  u32 r = u + 0x7fffu + ((u >> 16) & 1u);
  return (u16)(r >> 16);
}
__device__ __forceinline__ u32 pack_trunc(float lo, float hi){
  u32 a = __builtin_bit_cast(u32, lo);
  u32 b = __builtin_bit_cast(u32, hi);
  return (a >> 16) | (b & 0xffff0000u);
}
__device__ __forceinline__ void lds_load16(const void* g, void* l){
  __builtin_amdgcn_global_load_lds(
      (const __attribute__((address_space(1))) u32*)g,
      (__attribute__((address_space(3))) u32*)l, 16, 0, 0);
}

// ---------- k0a: Bt[n][k] = concat(W_enc,W_att)[k][n] as bf16 (512 x 1056) ----------
__global__ void k_build_bt(const float* __restrict__ W_enc,
                           const float* __restrict__ W_att,
                           u16* __restrict__ Bt){
  __shared__ float tile[32][33];
  int k0 = blockIdx.x * 32, n0 = blockIdx.y * 32;
  int tx = threadIdx.x & 31, ty = threadIdx.x >> 5;
  #pragma unroll
  for (int i = 0; i < 4; i++){
    int k = k0 + i*8 + ty;
    int n = n0 + tx;
    float v = (k < 1024) ? W_enc[k*512 + n] : W_att[(k-1024)*512 + n];
    tile[i*8+ty][tx] = v;
  }
  __syncthreads();
  #pragma unroll
  for (int i = 0; i < 4; i++){
    int n = n0 + i*8 + ty;
    int k = k0 + tx;
    Bt[(size_t)n*KAUG + k] = bf16_rn(tile[tx][i*8+ty]);
  }
}

// ---------- k0b: bias[b][n] = b_enc[n] + dec_z[b] @ W_dec[:,n]  (fp32) ----------
__global__ void k_bias(const float* __restrict__ dec_z,
                       const float* __restrict__ W_dec,
                       const float* __restrict__ b_enc,
                       float* __restrict__ bias){
  int b = blockIdx.x, n = threadIdx.x;   // 512 threads
  float s = b_enc[n];
  const float* dz = dec_z + b*1024;
  #pragma unroll 4
  for (int k = 0; k < 1024; k++) s += dz[k] * W_dec[k*512 + n];
  bias[b*512 + n] = s;
}

// ---------- k0c: attT[b*2048+t][c] = conv1d(att_prev)[b][c][t]  (65536 x 32 fp32) ----------
__global__ void k_conv(const float* __restrict__ att_prev,
                       const float* __restrict__ conv_w,
                       float* __restrict__ attT){
  int idx = blockIdx.x*256 + threadIdx.x;     // 65536*32 total
  int c = idx & 31;
  int bt = idx >> 5;
  int b = bt >> 11, t = bt & 2047;
  const float* ap = att_prev + b*2048;
  const float* cw = conv_w + c*31;
  float s = 0.f;
  #pragma unroll
  for (int j = 0; j < 31; j++){
    int tt = t + j - 15;
    float a = (tt >= 0 && tt < 2048) ? ap[tt] : 0.f;
    s += cw[j] * a;
  }
  attT[(size_t)bt*32 + c] = s;
}

// ---------- GEMM + fused tanh/Wg epilogue -> ePart[nblk][65536] ----------
// A = [enc | attT] (65536 x 1056) fp32, staged fp32 to LDS via global_load_lds,
// converted to bf16 at fragment read (truncation). B = Bt (n-major) bf16.
// XOR chunk swizzle (applied on the global gather side) breaks LDS bank clustering.
__launch_bounds__(256)
__global__ void k_gemm_energy(const float* __restrict__ enc,
                              const float* __restrict__ attT,
                              const u16* __restrict__ Bt,
                              const float* __restrict__ bias,
                              const float* __restrict__ Wg,
                              float* __restrict__ ePart){
  __shared__ float Ash[128*32];     // 16 KB  (rows of 8 chunks x 16B, swizzled)
  __shared__ u16   Bsh[128*32];     // 8 KB   (rows of 4 chunks x 16B, swizzled)
  __shared__ float eRed[2][128];

  const int tid  = threadIdx.x;
  const int lane = tid & 63;
  const int wid  = tid >> 6;
  const int wave_m = wid >> 1, wave_n = wid & 1;
  const int nblk = blockIdx.x;          // 0..3
  const int mblk = blockIdx.y;          // 0..511
  const int row0 = mblk << 7;
  const int b    = mblk >> 4;           // 16 M-tiles per batch row

  f32x4 acc[4][4];
  #pragma unroll
  for (int i = 0; i < 4; i++)
    #pragma unroll
    for (int j = 0; j < 4; j++) acc[i][j] = (f32x4)(0.f);

  const int arow_in = lane >> 3;   // A staging: 8 rows / issue
  const int ap_phys = lane & 7;
  const int brow_in = lane >> 2;   // B staging: 16 rows / issue
  const int bp_phys = lane & 3;
  const int fr_m = lane & 15;      // fragment lane coords
  const int kg   = lane >> 4;

  const u16* BtN = Bt + (size_t)(nblk*128)*KAUG;

  #pragma unroll 1
  for (int kk = 0; kk < 33; ++kk){
    const float* srcA; int rstr;
    if (kk < 32){ srcA = enc  + (size_t)row0*1024 + kk*32; rstr = 1024; }
    else        { srcA = attT + (size_t)row0*32;           rstr = 32;   }
    // stage A: 4 issues x (8 rows x 128B)
    #pragma unroll
    for (int q = 0; q < 4; q++){
      int r = wid*32 + q*8 + arow_in;
      int c = ap_phys ^ (r & 7);
      lds_load16(srcA + (size_t)r*rstr + c*4, Ash + (wid*32 + q*8)*32);
    }
    // stage B: 2 issues x (16 rows x 64B)
    const u16* srcB = BtN + kk*32;
    #pragma unroll
    for (int q = 0; q < 2; q++){
      int n = wid*32 + q*16 + brow_in;
      int c = bp_phys ^ ((n >> 1) & 3);
      lds_load16(srcB + (size_t)n*KAUG + c*8, Bsh + (wid*32 + q*16)*32);
    }
    __syncthreads();

    short8 afrag[4], bfrag[4];
    #pragma unroll
    for (int mi = 0; mi < 4; mi++){
      int m  = wave_m*64 + mi*16 + fr_m;
      int c0 = kg*2;
      int p0 = c0 ^ (m & 7), p1 = (c0+1) ^ (m & 7);
      const f32x4* rowp = (const f32x4*)(Ash + m*32);
      f32x4 x0 = rowp[p0];
      f32x4 x1 = rowp[p1];
      union { u32 u[4]; short8 s; } cv;
      cv.u[0] = pack_trunc(x0.x, x0.y);
      cv.u[1] = pack_trunc(x0.z, x0.w);
      cv.u[2] = pack_trunc(x1.x, x1.y);
      cv.u[3] = pack_trunc(x1.z, x1.w);
      afrag[mi] = cv.s;
    }
    #pragma unroll
    for (int ni = 0; ni < 4; ni++){
      int n = wave_n*64 + ni*16 + fr_m;
      int p = kg ^ ((n >> 1) & 3);
      bfrag[ni] = *(const short8*)(Bsh + n*32 + p*8);
    }
    #pragma unroll
    for (int mi = 0; mi < 4; mi++)
      #pragma unroll
      for (int ni = 0; ni < 4; ni++)
        acc[mi][ni] = __builtin_amdgcn_mfma_f32_16x16x32_bf16(afrag[mi], bfrag[ni], acc[mi][ni], 0, 0, 0);

    __syncthreads();
  }

  // epilogue: e_partial[row] = sum_n Wg[n] * tanh(acc + bias[b][n]) over this block's 128 n
  float wg[4], bs[4];
  #pragma unroll
  for (int ni = 0; ni < 4; ni++){
    int ng = nblk*128 + wave_n*64 + ni*16 + fr_m;
    wg[ni] = Wg[ng];
    bs[ni] = bias[b*512 + ng];
  }
  #pragma unroll
  for (int mi = 0; mi < 4; mi++){
    #pragma unroll
    for (int reg = 0; reg < 4; reg++){
      float s = 0.f;
      #pragma unroll
      for (int ni = 0; ni < 4; ni++){
        float v  = acc[mi][ni][reg] + bs[ni];
        float e2 = __expf(2.f * v);
        float th = 1.f - 2.f/(e2 + 1.f);   // tanh(v); saturates correctly at +/-1
        s += wg[ni] * th;
      }
      s += __shfl_xor(s, 1);
      s += __shfl_xor(s, 2);
      s += __shfl_xor(s, 4);
      s += __shfl_xor(s, 8);
      if (fr_m == 0){
        int rowl = wave_m*64 + mi*16 + kg*4 + reg;
        eRed[wave_n][rowl] = s;
      }
    }
  }
  __syncthreads();
  if (tid < 128)
    ePart[(size_t)nblk*M_TOT + row0 + tid] = eRed[0][tid] + eRed[1][tid];
}

// ---------- masked softmax over T per batch (SCALING=2; b_g cancels) ----------
__global__ void k_softmax(const float* __restrict__ ePart,
                          const int* __restrict__ lens,
                          float* __restrict__ wout){
  int b = blockIdx.x, tid = threadIdx.x;
  int lane = tid & 63, wid = tid >> 6;
  int len = lens[b];
  __shared__ float red[4];
  float x[8]; float m = -3.0e38f;
  #pragma unroll
  for (int i = 0; i < 8; i++){
    int t = tid + i*256;
    int idx = b*2048 + t;
    float e = ePart[idx] + ePart[M_TOT + idx] + ePart[2*M_TOT + idx] + ePart[3*M_TOT + idx];
    float xx = (t < len) ? 2.0f*e : -3.0e38f;
    x[i] = xx; m = fmaxf(m, xx);
  }
  #pragma unroll
  for (int o = 1; o < 64; o <<= 1) m = fmaxf(m, __shfl_xor(m, o));
  if (lane == 0) red[wid] = m;
  __syncthreads();
  m = fmaxf(fmaxf(red[0], red[1]), fmaxf(red[2], red[3]));
  float s = 0.f;
  #pragma unroll
  for (int i = 0; i < 8; i++){
    float ex = (x[i] > -1.0e38f) ? __expf(x[i] - m) : 0.f;
    x[i] = ex; s += ex;
  }
  #pragma unroll
  for (int o = 1; o < 64; o <<= 1) s += __shfl_xor(s, o);
  __syncthreads();
  if (lane == 0) red[wid] = s;
  __syncthreads();
  s = red[0] + red[1] + red[2] + red[3];
  float inv = 1.0f / s;
  #pragma unroll
  for (int i = 0; i < 8; i++){
    int t = tid + i*256;
    wout[b*2048 + t] = x[i]*inv;
  }
}

// ---------- context: cPart[tc][b][d] = sum_{t in tc} w[b,t]*enc[b,t,d] ----------
__global__ void k_ctx_partial(const float* __restrict__ enc,
                              const float* __restrict__ w,
                              float* __restrict__ cPart){
  int dc = blockIdx.x, tc = blockIdx.y, b = blockIdx.z;
  int d = dc*256 + threadIdx.x;
  const float* ep = enc + ((size_t)(b*2048 + tc*256))*1024 + d;
  const float* wp = w + b*2048 + tc*256;
  float s0 = 0, s1 = 0, s2 = 0, s3 = 0;
  #pragma unroll 2
  for (int t = 0; t < 256; t += 4){
    s0 += wp[t+0] * ep[(size_t)(t+0)*1024];
    s1 += wp[t+1] * ep[(size_t)(t+1)*1024];
    s2 += wp[t+2] * ep[(size_t)(t+2)*1024];
    s3 += wp[t+3] * ep[(size_t)(t+3)*1024];
  }
  cPart[((size_t)tc*32 + b)*1024 + d] = (s0 + s1) + (s2 + s3);
}

__global__ void k_ctx_reduce(const float* __restrict__ cPart, float* __restrict__ cOut){
  int idx = blockIdx.x*256 + threadIdx.x;   // 32768
  float s = 0.f;
  #pragma unroll
  for (int tc = 0; tc < 8; tc++) s += cPart[tc*32768 + idx];
  cOut[idx] = s;
}

extern "C" void kernel_launch(void* const* d_in, const int* in_sizes, int n_in,
                              void* d_out, int out_size, void* d_ws, size_t ws_size,
                              hipStream_t stream){
  (void)in_sizes; (void)n_in; (void)out_size; (void)ws_size;
  const float* enc    = (const float*)d_in[0];
  const int*   lens   = (const int*)  d_in[1];
  const float* dec_z  = (const float*)d_in[2];
  const float* att_p  = (const float*)d_in[3];
  const float* W_enc  = (const float*)d_in[4];
  const float* b_enc  = (const float*)d_in[5];
  const float* W_dec  = (const float*)d_in[6];
  const float* W_att  = (const float*)d_in[7];
  const float* conv_w = (const float*)d_in[8];
  const float* W_g    = (const float*)d_in[9];
  // d_in[10] = b_g: cancels inside softmax, unused.

  char* ws = (char*)d_ws;
  u16*   Bt    = (u16*)  (ws);                                        // 1,081,344 B
  float* attT  = (float*)(ws + 1081344);                              // 8,388,608 B
  float* bias  = (float*)(ws + 1081344 + 8388608);                    // 65,536 B
  float* ePart = (float*)(ws + 1081344 + 8388608 + 65536);            // 1,048,576 B
  float* cPart = (float*)(ws + 1081344 + 8388608 + 65536 + 1048576);  // 1,048,576 B

  float* c_out = (float*)d_out;          // (32,1024)
  float* w_out = c_out + 32*1024;        // (32,2048)

  hipLaunchKernelGGL(k_build_bt,    dim3(33,16),  dim3(256), 0, stream, W_enc, W_att, Bt);
  hipLaunchKernelGGL(k_bias,        dim3(32),     dim3(512), 0, stream, dec_z, W_dec, b_enc, bias);
  hipLaunchKernelGGL(k_conv,        dim3(8192),   dim3(256), 0, stream, att_p, conv_w, attT);
  hipLaunchKernelGGL(k_gemm_energy, dim3(4,512),  dim3(256), 0, stream, enc, attT, Bt, bias, W_g, ePart);
  hipLaunchKernelGGL(k_softmax,     dim3(32),     dim3(256), 0, stream, ePart, lens, w_out);
  hipLaunchKernelGGL(k_ctx_partial, dim3(4,8,32), dim3(256), 0, stream, enc, w_out, cPart);
  hipLaunchKernelGGL(k_ctx_reduce,  dim3(128),    dim3(256), 0, stream, cPart, c_out);
}

// Round 2
// 594.269 us; speedup vs baseline: 1.1541x; 1.1541x over previous
//
#include <hip/hip_runtime.h>
#include <stdint.h>

#define T_LEN 2048
#define KAUG  1056
#define M_TOT 65536

typedef __attribute__((ext_vector_type(8))) short short8;
typedef __attribute__((ext_vector_type(4))) float f32x4;
typedef unsigned int u32;
typedef unsigned short u16;

__device__ __forceinline__ u16 bf16_rn(float f){
  u32 u = __builtin_bit_cast(u32, f);
  u32 r = u + 0x7fffu + ((u >> 16) & 1u);
  return (u16)(r >> 16);
}
__device__ __forceinline__ u32 pack_trunc(float lo, float hi){
  u32 a = __builtin_bit_cast(u32, lo);
  u32 b = __builtin_bit_cast(u32, hi);
  return (a >> 16) | (b & 0xffff0000u);
}
__device__ __forceinline__ void lds_load16(const void* g, void* l){
  __builtin_amdgcn_global_load_lds(
      (const __attribute__((address_space(1))) u32*)g,
      (__attribute__((address_space(3))) u32*)l, 16, 0, 0);
}

// ---------- k0a: Bt[n][k] = concat(W_enc,W_att)[k][n] as bf16 (512 x 1056) ----------
__global__ void k_build_bt(const float* __restrict__ W_enc,
                           const float* __restrict__ W_att,
                           u16* __restrict__ Bt){
  __shared__ float tile[32][33];
  int k0 = blockIdx.x * 32, n0 = blockIdx.y * 32;
  int tx = threadIdx.x & 31, ty = threadIdx.x >> 5;
  #pragma unroll
  for (int i = 0; i < 4; i++){
    int k = k0 + i*8 + ty;
    int n = n0 + tx;
    float v = (k < 1024) ? W_enc[k*512 + n] : W_att[(k-1024)*512 + n];
    tile[i*8+ty][tx] = v;
  }
  __syncthreads();
  #pragma unroll
  for (int i = 0; i < 4; i++){
    int n = n0 + i*8 + ty;
    int k = k0 + tx;
    Bt[(size_t)n*KAUG + k] = bf16_rn(tile[tx][i*8+ty]);
  }
}

// ---------- k0b: bias[b][n] = b_enc[n] + dec_z[b] @ W_dec[:,n]  (fp32, split-K) ----------
__global__ void k_bias(const float* __restrict__ dec_z,
                       const float* __restrict__ W_dec,
                       const float* __restrict__ b_enc,
                       float* __restrict__ bias){
  __shared__ float red[4][64];
  int b = blockIdx.y, n0 = blockIdx.x * 64;          // grid (8,32)
  int nl = threadIdx.x & 63, ks = threadIdx.x >> 6;  // 4 k-slices of 256
  int n = n0 + nl;
  const float* dz = dec_z + b*1024;
  float s = 0.f;
  #pragma unroll 4
  for (int k = ks*256; k < ks*256 + 256; k++) s += dz[k] * W_dec[k*512 + n];
  red[ks][nl] = s;
  __syncthreads();
  if (threadIdx.x < 64){
    int nn = n0 + threadIdx.x;
    bias[b*512 + nn] = b_enc[nn] + red[0][threadIdx.x] + red[1][threadIdx.x]
                     + red[2][threadIdx.x] + red[3][threadIdx.x];
  }
}

// ---------- k0c: attT[b*2048+t][c] = conv1d(att_prev)[b][c][t]  (65536 x 32 fp32) ----------
__global__ void k_conv(const float* __restrict__ att_prev,
                       const float* __restrict__ conv_w,
                       float* __restrict__ attT){
  int idx = blockIdx.x*256 + threadIdx.x;     // 65536*32 total
  int c = idx & 31;
  int bt = idx >> 5;
  int b = bt >> 11, t = bt & 2047;
  const float* ap = att_prev + b*2048;
  const float* cw = conv_w + c*31;
  float s = 0.f;
  #pragma unroll
  for (int j = 0; j < 31; j++){
    int tt = t + j - 15;
    float a = (tt >= 0 && tt < 2048) ? ap[tt] : 0.f;
    s += cw[j] * a;
  }
  attT[(size_t)bt*32 + c] = s;
}

// ---------- GEMM + fused tanh/Wg epilogue -> ePart[nblk][65536] ----------
// A = [enc | attT] (65536 x 1056) fp32, staged fp32 to LDS via global_load_lds,
// converted to bf16 at fragment read (truncation). B = Bt (n-major) bf16.
// XOR chunk swizzle (applied on the global gather side) breaks LDS bank clustering.
// Grid is 1D-swizzled so the 4 nblk-siblings of each mblk land on the SAME XCD
// (consecutive per-XCD dispatch slots, assuming round-robin idx%8 placement):
// one sibling's HBM miss fills that XCD's L2, the other three hit L2.
__launch_bounds__(256)
__global__ void k_gemm_energy(const float* __restrict__ enc,
                              const float* __restrict__ attT,
                              const u16* __restrict__ Bt,
                              const float* __restrict__ bias,
                              const float* __restrict__ Wg,
                              float* __restrict__ ePart){
  __shared__ float Ash[128*32];     // 16 KB  (rows of 8 chunks x 16B, swizzled)
  __shared__ u16   Bsh[128*32];     // 8 KB   (rows of 4 chunks x 16B, swizzled)
  __shared__ float eRed[2][128];

  const int tid  = threadIdx.x;
  const int lane = tid & 63;
  const int wid  = tid >> 6;
  const int wave_m = wid >> 1, wave_n = wid & 1;
  // XCD-sibling swizzle
  const int bidx = blockIdx.x;            // 0..2047
  const int xcd  = bidx & 7;
  const int s_sq = bidx >> 3;             // per-XCD sequence 0..255
  const int nblk = s_sq & 3;              // 4 consecutive same-XCD slots share mblk
  const int mblk = ((s_sq >> 2) << 3) + xcd;   // 0..511
  const int row0 = mblk << 7;
  const int b    = mblk >> 4;             // 16 M-tiles per batch row

  f32x4 acc[4][4];
  #pragma unroll
  for (int i = 0; i < 4; i++)
    #pragma unroll
    for (int j = 0; j < 4; j++) acc[i][j] = (f32x4)(0.f);

  const int arow_in = lane >> 3;   // A staging: 8 rows / issue
  const int ap_phys = lane & 7;
  const int brow_in = lane >> 2;   // B staging: 16 rows / issue
  const int bp_phys = lane & 3;
  const int fr_m = lane & 15;      // fragment lane coords
  const int kg   = lane >> 4;

  const u16* BtN = Bt + (size_t)(nblk*128)*KAUG;

  #pragma unroll 1
  for (int kk = 0; kk < 33; ++kk){
    const float* srcA; int rstr;
    if (kk < 32){ srcA = enc  + (size_t)row0*1024 + kk*32; rstr = 1024; }
    else        { srcA = attT + (size_t)row0*32;           rstr = 32;   }
    // stage A: 4 issues x (8 rows x 128B)
    #pragma unroll
    for (int q = 0; q < 4; q++){
      int r = wid*32 + q*8 + arow_in;
      int c = ap_phys ^ (r & 7);
      lds_load16(srcA + (size_t)r*rstr + c*4, Ash + (wid*32 + q*8)*32);
    }
    // stage B: 2 issues x (16 rows x 64B)
    const u16* srcB = BtN + kk*32;
    #pragma unroll
    for (int q = 0; q < 2; q++){
      int n = wid*32 + q*16 + brow_in;
      int c = bp_phys ^ ((n >> 1) & 3);
      lds_load16(srcB + (size_t)n*KAUG + c*8, Bsh + (wid*32 + q*16)*32);
    }
    __syncthreads();

    short8 afrag[4], bfrag[4];
    #pragma unroll
    for (int mi = 0; mi < 4; mi++){
      int m  = wave_m*64 + mi*16 + fr_m;
      int c0 = kg*2;
      int p0 = c0 ^ (m & 7), p1 = (c0+1) ^ (m & 7);
      const f32x4* rowp = (const f32x4*)(Ash + m*32);
      f32x4 x0 = rowp[p0];
      f32x4 x1 = rowp[p1];
      union { u32 u[4]; short8 s; } cv;
      cv.u[0] = pack_trunc(x0.x, x0.y);
      cv.u[1] = pack_trunc(x0.z, x0.w);
      cv.u[2] = pack_trunc(x1.x, x1.y);
      cv.u[3] = pack_trunc(x1.z, x1.w);
      afrag[mi] = cv.s;
    }
    #pragma unroll
    for (int ni = 0; ni < 4; ni++){
      int n = wave_n*64 + ni*16 + fr_m;
      int p = kg ^ ((n >> 1) & 3);
      bfrag[ni] = *(const short8*)(Bsh + n*32 + p*8);
    }
    #pragma unroll
    for (int mi = 0; mi < 4; mi++)
      #pragma unroll
      for (int ni = 0; ni < 4; ni++)
        acc[mi][ni] = __builtin_amdgcn_mfma_f32_16x16x32_bf16(afrag[mi], bfrag[ni], acc[mi][ni], 0, 0, 0);

    __syncthreads();
  }

  // epilogue: e_partial[row] = sum_n Wg[n] * tanh(acc + bias[b][n]) over this block's 128 n
  float wg[4], bs[4];
  #pragma unroll
  for (int ni = 0; ni < 4; ni++){
    int ng = nblk*128 + wave_n*64 + ni*16 + fr_m;
    wg[ni] = Wg[ng];
    bs[ni] = bias[b*512 + ng];
  }
  #pragma unroll
  for (int mi = 0; mi < 4; mi++){
    #pragma unroll
    for (int reg = 0; reg < 4; reg++){
      float s = 0.f;
      #pragma unroll
      for (int ni = 0; ni < 4; ni++){
        float v  = acc[mi][ni][reg] + bs[ni];
        float e2 = __expf(2.f * v);
        float th = 1.f - 2.f/(e2 + 1.f);   // tanh(v); saturates correctly at +/-1
        s += wg[ni] * th;
      }
      s += __shfl_xor(s, 1);
      s += __shfl_xor(s, 2);
      s += __shfl_xor(s, 4);
      s += __shfl_xor(s, 8);
      if (fr_m == 0){
        int rowl = wave_m*64 + mi*16 + kg*4 + reg;
        eRed[wave_n][rowl] = s;
      }
    }
  }
  __syncthreads();
  if (tid < 128)
    ePart[(size_t)nblk*M_TOT + row0 + tid] = eRed[0][tid] + eRed[1][tid];
}

// ---------- masked softmax over T per batch (SCALING=2; b_g cancels) ----------
__global__ void k_softmax(const float* __restrict__ ePart,
                          const int* __restrict__ lens,
                          float* __restrict__ wout){
  int b = blockIdx.x, tid = threadIdx.x;
  int lane = tid & 63, wid = tid >> 6;
  int len = lens[b];
  __shared__ float red[4];
  float x[8]; float m = -3.0e38f;
  #pragma unroll
  for (int i = 0; i < 8; i++){
    int t = tid + i*256;
    int idx = b*2048 + t;
    float e = ePart[idx] + ePart[M_TOT + idx] + ePart[2*M_TOT + idx] + ePart[3*M_TOT + idx];
    float xx = (t < len) ? 2.0f*e : -3.0e38f;
    x[i] = xx; m = fmaxf(m, xx);
  }
  #pragma unroll
  for (int o = 1; o < 64; o <<= 1) m = fmaxf(m, __shfl_xor(m, o));
  if (lane == 0) red[wid] = m;
  __syncthreads();
  m = fmaxf(fmaxf(red[0], red[1]), fmaxf(red[2], red[3]));
  float s = 0.f;
  #pragma unroll
  for (int i = 0; i < 8; i++){
    float ex = (x[i] > -1.0e38f) ? __expf(x[i] - m) : 0.f;
    x[i] = ex; s += ex;
  }
  #pragma unroll
  for (int o = 1; o < 64; o <<= 1) s += __shfl_xor(s, o);
  __syncthreads();
  if (lane == 0) red[wid] = s;
  __syncthreads();
  s = red[0] + red[1] + red[2] + red[3];
  float inv = 1.0f / s;
  #pragma unroll
  for (int i = 0; i < 8; i++){
    int t = tid + i*256;
    wout[b*2048 + t] = x[i]*inv;
  }
}

// ---------- context: cPart[tc][b][d] = sum_{t in tc} w[b,t]*enc[b,t,d] ----------
__global__ void k_ctx_partial(const float* __restrict__ enc,
                              const float* __restrict__ w,
                              float* __restrict__ cPart){
  int dc = blockIdx.x, tc = blockIdx.y, b = blockIdx.z;
  int d = dc*256 + threadIdx.x;
  const float* ep = enc + ((size_t)(b*2048 + tc*256))*1024 + d;
  const float* wp = w + b*2048 + tc*256;
  float s0 = 0, s1 = 0, s2 = 0, s3 = 0;
  #pragma unroll 2
  for (int t = 0; t < 256; t += 4){
    s0 += wp[t+0] * ep[(size_t)(t+0)*1024];
    s1 += wp[t+1] * ep[(size_t)(t+1)*1024];
    s2 += wp[t+2] * ep[(size_t)(t+2)*1024];
    s3 += wp[t+3] * ep[(size_t)(t+3)*1024];
  }
  cPart[((size_t)tc*32 + b)*1024 + d] = (s0 + s1) + (s2 + s3);
}

__global__ void k_ctx_reduce(const float* __restrict__ cPart, float* __restrict__ cOut){
  int idx = blockIdx.x*256 + threadIdx.x;   // 32768
  float s = 0.f;
  #pragma unroll
  for (int tc = 0; tc < 8; tc++) s += cPart[tc*32768 + idx];
  cOut[idx] = s;
}

extern "C" void kernel_launch(void* const* d_in, const int* in_sizes, int n_in,
                              void* d_out, int out_size, void* d_ws, size_t ws_size,
                              hipStream_t stream){
  (void)in_sizes; (void)n_in; (void)out_size; (void)ws_size;
  const float* enc    = (const float*)d_in[0];
  const int*   lens   = (const int*)  d_in[1];
  const float* dec_z  = (const float*)d_in[2];
  const float* att_p  = (const float*)d_in[3];
  const float* W_enc  = (const float*)d_in[4];
  const float* b_enc  = (const float*)d_in[5];
  const float* W_dec  = (const float*)d_in[6];
  const float* W_att  = (const float*)d_in[7];
  const float* conv_w = (const float*)d_in[8];
  const float* W_g    = (const float*)d_in[9];
  // d_in[10] = b_g: cancels inside softmax, unused.

  char* ws = (char*)d_ws;
  u16*   Bt    = (u16*)  (ws);                                        // 1,081,344 B
  float* attT  = (float*)(ws + 1081344);                              // 8,388,608 B
  float* bias  = (float*)(ws + 1081344 + 8388608);                    // 65,536 B
  float* ePart = (float*)(ws + 1081344 + 8388608 + 65536);            // 1,048,576 B
  float* cPart = (float*)(ws + 1081344 + 8388608 + 65536 + 1048576);  // 1,048,576 B

  float* c_out = (float*)d_out;          // (32,1024)
  float* w_out = c_out + 32*1024;        // (32,2048)

  hipLaunchKernelGGL(k_build_bt,    dim3(33,16),  dim3(256), 0, stream, W_enc, W_att, Bt);
  hipLaunchKernelGGL(k_bias,        dim3(8,32),   dim3(256), 0, stream, dec_z, W_dec, b_enc, bias);
  hipLaunchKernelGGL(k_conv,        dim3(8192),   dim3(256), 0, stream, att_p, conv_w, attT);
  hipLaunchKernelGGL(k_gemm_energy, dim3(2048),   dim3(256), 0, stream, enc, attT, Bt, bias, W_g, ePart);
  hipLaunchKernelGGL(k_softmax,     dim3(32),     dim3(256), 0, stream, ePart, lens, w_out);
  hipLaunchKernelGGL(k_ctx_partial, dim3(4,8,32), dim3(256), 0, stream, enc, w_out, cPart);
  hipLaunchKernelGGL(k_ctx_reduce,  dim3(128),    dim3(256), 0, stream, cPart, c_out);
}